// Round 1
// baseline (855.525 us; speedup 1.0000x reference)
//
#include <hip/hip_runtime.h>

typedef __attribute__((ext_vector_type(4))) float f32x4;
typedef __attribute__((ext_vector_type(8))) short bf16x8;
typedef unsigned int uint;
typedef unsigned short ushort;

// ---------- helpers ----------

__device__ __forceinline__ ushort f2bf(float f) {
  union { float f; uint u; } v; v.f = f;
  uint u = v.u;
  uint r = (u + 0x7FFFu + ((u >> 16) & 1u)) >> 16;  // RNE
  return (ushort)r;
}
__device__ __forceinline__ float to_f32(float f) { return f; }
__device__ __forceinline__ float to_f32(ushort u) {
  union { uint u; float f; } v; v.u = ((uint)u) << 16;
  return v.f;
}

__device__ __forceinline__ void gload_lds16(const void* g, void* l) {
  __builtin_amdgcn_global_load_lds(
      (const __attribute__((address_space(1))) void*)g,
      (__attribute__((address_space(3))) void*)l, 16, 0, 0);
}

// ---------- pre-pass kernels ----------

// f32 -> bf16, 8 elems/thread, exact grid
__global__ __launch_bounds__(256)
void conv_bf16(const float* __restrict__ in, ushort* __restrict__ out, long n) {
  long i = ((long)blockIdx.x * 256 + threadIdx.x) * 8;
  if (i >= n) return;
  float4 a = *(const float4*)(in + i);
  float4 b = *(const float4*)(in + i + 4);
  union { ushort u[8]; uint4 v; } o;
  o.u[0] = f2bf(a.x); o.u[1] = f2bf(a.y); o.u[2] = f2bf(a.z); o.u[3] = f2bf(a.w);
  o.u[4] = f2bf(b.x); o.u[5] = f2bf(b.y); o.u[6] = f2bf(b.z); o.u[7] = f2bf(b.w);
  *(uint4*)(out + i) = o.v;
}

// transpose [R][C] -> [C][R], output bf16. block (32,8), tile 32x32, batch in z
template<typename T>
__global__ __launch_bounds__(256)
void transpose_to_bf16(const T* __restrict__ in, ushort* __restrict__ out, int R, int C) {
  __shared__ float tile[32][33];
  const size_t boff = (size_t)blockIdx.z * R * C;
  in += boff; out += boff;
  const int r0 = blockIdx.y * 32, c0 = blockIdx.x * 32;
  const int x = threadIdx.x, y = threadIdx.y;
#pragma unroll
  for (int j = 0; j < 32; j += 8)
    tile[y + j][x] = to_f32(in[(size_t)(r0 + y + j) * C + c0 + x]);
  __syncthreads();
#pragma unroll
  for (int j = 0; j < 32; j += 8)
    out[(size_t)(c0 + y + j) * R + r0 + x] = f2bf(tile[x][y + j]);
}

// mask int32 [B*S][S] -> bit-packed u32 [B*S][S/32]; bit i of word j = (mask[32j+i] > 0)
__global__ __launch_bounds__(256)
void pack_mask(const int* __restrict__ in, uint* __restrict__ out) {
  long t = (long)blockIdx.x * 256 + threadIdx.x;  // one output word per thread
  const int4* p = (const int4*)(in + t * 32);
  uint w = 0;
#pragma unroll
  for (int i = 0; i < 8; ++i) {
    int4 v = p[i];
    w |= (v.x > 0 ? 1u : 0u) << (i * 4 + 0);
    w |= (v.y > 0 ? 1u : 0u) << (i * 4 + 1);
    w |= (v.z > 0 ? 1u : 0u) << (i * 4 + 2);
    w |= (v.w > 0 ? 1u : 0u) << (i * 4 + 3);
  }
  out[t] = w;
}

// ---------- GEMM: C[M][N] = A[M][K] * Bt[N][K]^T  (m97 structure) ----------
// 128x128 tile, BK=64, 4 waves (2x2), each wave 64x64 = 4x4 fragments of 16x16x32

template<int OUT_BF16>
__global__ __launch_bounds__(256)
void gemm_bt(const ushort* __restrict__ A, const ushort* __restrict__ Bt,
             void* __restrict__ C, int M, int N, int K, float scale) {
  __shared__ ushort lA[128 * 64];
  __shared__ ushort lB[128 * 64];
  const int tid = threadIdx.x;
  const int wid = tid >> 6;
  const int lane = tid & 63;
  const int lg = lane >> 4, li = lane & 15;
  const int m0 = blockIdx.y * 128;
  const int n0 = blockIdx.x * 128;
  const int wr = (wid >> 1) * 64;
  const int wc = (wid & 1) * 64;

  f32x4 acc[4][4] = {};
  const char* Ab = (const char*)A;
  const char* Bb = (const char*)Bt;

  for (int kt = 0; kt < K; kt += 64) {
    __syncthreads();  // previous compute done before restage
#pragma unroll
    for (int i = 0; i < 4; ++i) {
      int flat = i * 4096 + tid * 16;
      int row = flat >> 7;        // 128 B per row (64 bf16)
      int colb = flat & 127;
      gload_lds16(Ab + ((size_t)(m0 + row) * K + kt) * 2 + colb,
                  (char*)lA + i * 4096 + wid * 1024);
    }
#pragma unroll
    for (int i = 0; i < 4; ++i) {
      int flat = i * 4096 + tid * 16;
      int row = flat >> 7;
      int colb = flat & 127;
      gload_lds16(Bb + ((size_t)(n0 + row) * K + kt) * 2 + colb,
                  (char*)lB + i * 4096 + wid * 1024);
    }
    __syncthreads();  // staging visible (compiler drains vmcnt before barrier)
#pragma unroll
    for (int ks = 0; ks < 2; ++ks) {
      bf16x8 af[4], bfr[4];
#pragma unroll
      for (int m = 0; m < 4; ++m)
        af[m] = *(const bf16x8*)&lA[(wr + m * 16 + li) * 64 + ks * 32 + lg * 8];
#pragma unroll
      for (int n = 0; n < 4; ++n)
        bfr[n] = *(const bf16x8*)&lB[(wc + n * 16 + li) * 64 + ks * 32 + lg * 8];
#pragma unroll
      for (int m = 0; m < 4; ++m)
#pragma unroll
        for (int n = 0; n < 4; ++n)
          acc[m][n] = __builtin_amdgcn_mfma_f32_16x16x32_bf16(af[m], bfr[n], acc[m][n], 0, 0, 0);
    }
  }

  // epilogue: C/D layout row=(lane>>4)*4+r, col=lane&15
  const int r0 = m0 + wr + lg * 4;
  const int c0 = n0 + wc + li;
#pragma unroll
  for (int m = 0; m < 4; ++m)
#pragma unroll
    for (int n = 0; n < 4; ++n)
#pragma unroll
      for (int r = 0; r < 4; ++r) {
        size_t idx = (size_t)(r0 + m * 16 + r) * N + (c0 + n * 16);
        float v = acc[m][n][r] * scale;
        if (OUT_BF16) ((ushort*)C)[idx] = f2bf(v);
        else          ((float*)C)[idx]  = v;
      }
}

// ---------- flash attention ----------
// grid: (S/64 q-tiles, B*H). 4 waves; wave w owns q-rows [q0+16w, +16).
// KV tile = 64. K tile [64][128] and VT tile [128][64] staged via global_load_lds
// with XOR swizzle byte ^= ((row&7)<<4) applied on the GLOBAL SOURCE address
// (linear LDS dest) and again on the read side (rule 21).

__global__ __launch_bounds__(256)
void flash_attn(const ushort* __restrict__ Q, const ushort* __restrict__ K,
                const ushort* __restrict__ VT, const uint* __restrict__ maskp,
                ushort* __restrict__ X) {
  __shared__ ushort lK[64 * 128];   // [kv][hd], rows 256 B, swizzled
  __shared__ ushort lVT[128 * 64];  // [hd][kv], rows 128 B, swizzled
  __shared__ ushort lP[4][16 * 64]; // per-wave P tile [16 q][64 k], swizzled

  const int tid = threadIdx.x;
  const int wid = tid >> 6;
  const int lane = tid & 63;
  const int lg = lane >> 4, li = lane & 15;
  const int qt = blockIdx.x;
  const int bh = blockIdx.y;
  const int b = bh >> 4, h = bh & 15;
  const int q0 = qt * 64;

  // Q fragments (A-operand), resident for whole block: rows q0+16w+li, hd = kk*32+lg*8
  bf16x8 aq[4];
  {
    const ushort* qrow = Q + ((size_t)(b * 2048 + q0 + wid * 16 + li)) * 2048 + h * 128;
#pragma unroll
    for (int kk = 0; kk < 4; ++kk)
      aq[kk] = *(const bf16x8*)(qrow + kk * 32 + lg * 8);
  }

  f32x4 acc_o[8] = {};
  float mrow[4], lrow[4];
#pragma unroll
  for (int r = 0; r < 4; ++r) { mrow[r] = -3e38f; lrow[r] = 0.f; }

  const uint* mrowp = maskp + (size_t)(b * 2048 + q0 + wid * 16 + lg * 4) * 64;
  ushort* lp = lP[wid];

  for (int kv0 = 0; kv0 < 2048; kv0 += 64) {
    __syncthreads();  // all reads of lK/lVT from previous iter done
    // stage K tile (16 KB): rows 256 B
#pragma unroll
    for (int i = 0; i < 4; ++i) {
      int flat = i * 4096 + tid * 16;
      int row = flat >> 8;
      int colb = (flat & 255) ^ ((row & 7) << 4);  // pre-swizzled source
      gload_lds16((const char*)K + ((size_t)(b * 2048 + kv0 + row) * 2048 + h * 128) * 2 + colb,
                  (char*)lK + i * 4096 + wid * 1024);
    }
    // stage VT tile (16 KB): rows 128 B
#pragma unroll
    for (int i = 0; i < 4; ++i) {
      int flat = i * 4096 + tid * 16;
      int row = flat >> 7;
      int colb = (flat & 127) ^ ((row & 7) << 4);
      gload_lds16((const char*)VT + ((size_t)((b * 16 + h) * 128 + row) * 2048 + kv0) * 2 + colb,
                  (char*)lVT + i * 4096 + wid * 1024);
    }
    __syncthreads();

    // QK^T: S[q 16][k 64] per wave, K-loop over hd (4 x 32)
    f32x4 accs[4] = {};
#pragma unroll
    for (int kk = 0; kk < 4; ++kk) {
#pragma unroll
      for (int n = 0; n < 4; ++n) {
        bf16x8 bk = *(const bf16x8*)((const char*)lK + (n * 16 + li) * 256 +
                                     (((kk * 64 + lg * 16)) ^ ((li & 7) << 4)));
        accs[n] = __builtin_amdgcn_mfma_f32_16x16x32_bf16(aq[kk], bk, accs[n], 0, 0, 0);
      }
    }

    // mask + online softmax (per q-row r; 64 k-values live in 16-lane group x 4 frags)
    float p[4][4];
#pragma unroll
    for (int r = 0; r < 4; ++r) {
      uint w0 = mrowp[(size_t)r * 64 + (kv0 >> 5)];
      uint w1 = mrowp[(size_t)r * 64 + (kv0 >> 5) + 1];
      float sv[4];
      float smax = -3e38f;
#pragma unroll
      for (int n = 0; n < 4; ++n) {
        uint w = (n < 2) ? w0 : w1;
        int pos = (n & 1) * 16 + li;
        float s = accs[n][r] + (((w >> pos) & 1u) ? 0.0f : -1e10f);
        sv[n] = s;
        smax = fmaxf(smax, s);
      }
#pragma unroll
      for (int d = 1; d < 16; d <<= 1)
        smax = fmaxf(smax, __shfl_xor(smax, d, 64));
      float mnew = fmaxf(mrow[r], smax);
      float alpha = __expf(mrow[r] - mnew);
      float sum = 0.f;
#pragma unroll
      for (int n = 0; n < 4; ++n) {
        float pv = __expf(sv[n] - mnew);
        p[n][r] = pv;
        sum += pv;
      }
#pragma unroll
      for (int d = 1; d < 16; d <<= 1)
        sum += __shfl_xor(sum, d, 64);
      lrow[r] = lrow[r] * alpha + sum;
      mrow[r] = mnew;
#pragma unroll
      for (int f = 0; f < 8; ++f) acc_o[f][r] *= alpha;
    }

    // P -> LDS (bf16), swizzled, per-wave region; row = q-local = lg*4+r, col = n*16+li
#pragma unroll
    for (int n = 0; n < 4; ++n)
#pragma unroll
      for (int r = 0; r < 4; ++r) {
        int row = lg * 4 + r;
        *(ushort*)((char*)lp + row * 128 + (((n * 32 + li * 2)) ^ ((row & 7) << 4))) =
            f2bf(p[n][r]);
      }
    __syncthreads();  // lP visible (and ordered) for all lanes

    // PV: A = P[16 q][64 k] from lP, B^T = VT rows; acc_o[f] covers hd = f*16+li
#pragma unroll
    for (int ks = 0; ks < 2; ++ks) {
      bf16x8 ap = *(const bf16x8*)((const char*)lp + li * 128 +
                                   (((ks * 64 + lg * 16)) ^ ((li & 7) << 4)));
#pragma unroll
      for (int f = 0; f < 8; ++f) {
        bf16x8 bv = *(const bf16x8*)((const char*)lVT + (f * 16 + li) * 128 +
                                     (((ks * 64 + lg * 16)) ^ ((li & 7) << 4)));
        acc_o[f] = __builtin_amdgcn_mfma_f32_16x16x32_bf16(ap, bv, acc_o[f], 0, 0, 0);
      }
    }
  }

  // epilogue: X[b*S+q][h*128+hd] = acc_o / l
#pragma unroll
  for (int f = 0; f < 8; ++f)
#pragma unroll
    for (int r = 0; r < 4; ++r) {
      size_t row = (size_t)(b * 2048 + q0 + wid * 16 + lg * 4 + r);
      X[row * 2048 + h * 128 + f * 16 + li] = f2bf(acc_o[f][r] / lrow[r]);
    }
}

// ---------- launch ----------

extern "C" void kernel_launch(void* const* d_in, const int* in_sizes, int n_in,
                              void* d_out, int out_size, void* d_ws, size_t ws_size,
                              hipStream_t stream) {
  const float* inputs_q  = (const float*)d_in[0];
  const float* inputs_kv = (const float*)d_in[1];
  const int*   mask      = (const int*)d_in[2];
  const float* Wq        = (const float*)d_in[3];
  const float* Wk        = (const float*)d_in[4];
  const float* Wv        = (const float*)d_in[5];
  const float* Wo        = (const float*)d_in[6];
  float* out = (float*)d_out;
  char* ws = (char*)d_ws;

  // workspace layout (bytes); peak ~203.5 MB
  uint*   maskp = (uint*)(ws + 0);                 //   2,097,152
  ushort* xq    = (ushort*)(ws + 2097152);         //  33,554,432 (reused as VT)
  ushort* xkv   = (ushort*)(ws + 35651584);        //  33,554,432 (reused as X)
  ushort* WqT   = (ushort*)(ws + 69206016);        //   8,388,608
  ushort* WkT   = (ushort*)(ws + 77594624);
  ushort* WvT   = (ushort*)(ws + 85983232);
  ushort* WoT   = (ushort*)(ws + 94371840);
  ushort* Qb    = (ushort*)(ws + 102760448);       //  33,554,432
  ushort* Kb    = (ushort*)(ws + 136314880);
  ushort* Vb    = (ushort*)(ws + 169869312);
  ushort* VTb   = xq;   // V^T [B*H*128][2048], written after xq is dead
  ushort* Xb    = xkv;  // attention output, written after xkv is dead

  const long NE = 8192L * 2048;  // activation elems
  conv_bf16<<<8192, 256, 0, stream>>>(inputs_q,  xq,  NE);
  conv_bf16<<<8192, 256, 0, stream>>>(inputs_kv, xkv, NE);

  dim3 tb(32, 8);
  transpose_to_bf16<float><<<dim3(64, 64, 1), tb, 0, stream>>>(Wq, WqT, 2048, 2048);
  transpose_to_bf16<float><<<dim3(64, 64, 1), tb, 0, stream>>>(Wk, WkT, 2048, 2048);
  transpose_to_bf16<float><<<dim3(64, 64, 1), tb, 0, stream>>>(Wv, WvT, 2048, 2048);
  transpose_to_bf16<float><<<dim3(64, 64, 1), tb, 0, stream>>>(Wo, WoT, 2048, 2048);

  pack_mask<<<2048, 256, 0, stream>>>(mask, maskp);

  const float qscale = 0.08838834764831845f;  // 1/sqrt(128)
  gemm_bt<1><<<dim3(16, 64), 256, 0, stream>>>(xq,  WqT, Qb, 8192, 2048, 2048, qscale);
  gemm_bt<1><<<dim3(16, 64), 256, 0, stream>>>(xkv, WkT, Kb, 8192, 2048, 2048, 1.0f);
  gemm_bt<1><<<dim3(16, 64), 256, 0, stream>>>(xkv, WvT, Vb, 8192, 2048, 2048, 1.0f);

  // V^T per batch: [2048 s][2048 (h,hd)] -> [2048 (h,hd)][2048 s]
  transpose_to_bf16<ushort><<<dim3(64, 64, 4), tb, 0, stream>>>(Vb, VTb, 2048, 2048);

  flash_attn<<<dim3(32, 64), 256, 0, stream>>>(Qb, Kb, VTb, maskp, Xb);

  gemm_bt<0><<<dim3(16, 64), 256, 0, stream>>>(Xb, WoT, out, 8192, 2048, 2048, 1.0f);
}

// Round 2
// 768.639 us; speedup vs baseline: 1.1130x; 1.1130x over previous
//
#include <hip/hip_runtime.h>

typedef __attribute__((ext_vector_type(4))) float f32x4;
typedef __attribute__((ext_vector_type(8))) short bf16x8;
typedef unsigned int uint;
typedef unsigned short ushort;

// ---------- helpers ----------

__device__ __forceinline__ ushort f2bf(float f) {
  union { float f; uint u; } v; v.f = f;
  uint u = v.u;
  uint r = (u + 0x7FFFu + ((u >> 16) & 1u)) >> 16;  // RNE
  return (ushort)r;
}
__device__ __forceinline__ float to_f32(float f) { return f; }
__device__ __forceinline__ float to_f32(ushort u) {
  union { uint u; float f; } v; v.u = ((uint)u) << 16;
  return v.f;
}

__device__ __forceinline__ void gload_lds16(const void* g, void* l) {
  __builtin_amdgcn_global_load_lds(
      (const __attribute__((address_space(1))) void*)g,
      (__attribute__((address_space(3))) void*)l, 16, 0, 0);
}

// ---------- pre-pass kernels ----------

__global__ __launch_bounds__(256)
void conv_bf16(const float* __restrict__ in, ushort* __restrict__ out, long n) {
  long i = ((long)blockIdx.x * 256 + threadIdx.x) * 8;
  if (i >= n) return;
  float4 a = *(const float4*)(in + i);
  float4 b = *(const float4*)(in + i + 4);
  union { ushort u[8]; uint4 v; } o;
  o.u[0] = f2bf(a.x); o.u[1] = f2bf(a.y); o.u[2] = f2bf(a.z); o.u[3] = f2bf(a.w);
  o.u[4] = f2bf(b.x); o.u[5] = f2bf(b.y); o.u[6] = f2bf(b.z); o.u[7] = f2bf(b.w);
  *(uint4*)(out + i) = o.v;
}

template<typename T>
__global__ __launch_bounds__(256)
void transpose_to_bf16(const T* __restrict__ in, ushort* __restrict__ out, int R, int C) {
  __shared__ float tile[32][33];
  const size_t boff = (size_t)blockIdx.z * R * C;
  in += boff; out += boff;
  const int r0 = blockIdx.y * 32, c0 = blockIdx.x * 32;
  const int x = threadIdx.x, y = threadIdx.y;
#pragma unroll
  for (int j = 0; j < 32; j += 8)
    tile[y + j][x] = to_f32(in[(size_t)(r0 + y + j) * C + c0 + x]);
  __syncthreads();
#pragma unroll
  for (int j = 0; j < 32; j += 8)
    out[(size_t)(c0 + y + j) * R + r0 + x] = f2bf(tile[x][y + j]);
}

__global__ __launch_bounds__(256)
void pack_mask(const int* __restrict__ in, uint* __restrict__ out) {
  long t = (long)blockIdx.x * 256 + threadIdx.x;
  const int4* p = (const int4*)(in + t * 32);
  uint w = 0;
#pragma unroll
  for (int i = 0; i < 8; ++i) {
    int4 v = p[i];
    w |= (v.x > 0 ? 1u : 0u) << (i * 4 + 0);
    w |= (v.y > 0 ? 1u : 0u) << (i * 4 + 1);
    w |= (v.z > 0 ? 1u : 0u) << (i * 4 + 2);
    w |= (v.w > 0 ? 1u : 0u) << (i * 4 + 3);
  }
  out[t] = w;
}

// ---------- GEMM: C[M][N] = A[M][K] * Bt[N][K]^T  (m97 structure, unchanged) ----

template<int OUT_BF16>
__global__ __launch_bounds__(256)
void gemm_bt(const ushort* __restrict__ A, const ushort* __restrict__ Bt,
             void* __restrict__ C, int M, int N, int K, float scale) {
  __shared__ ushort lA[128 * 64];
  __shared__ ushort lB[128 * 64];
  const int tid = threadIdx.x;
  const int wid = tid >> 6;
  const int lane = tid & 63;
  const int lg = lane >> 4, li = lane & 15;
  const int m0 = blockIdx.y * 128;
  const int n0 = blockIdx.x * 128;
  const int wr = (wid >> 1) * 64;
  const int wc = (wid & 1) * 64;

  f32x4 acc[4][4] = {};
  const char* Ab = (const char*)A;
  const char* Bb = (const char*)Bt;

  for (int kt = 0; kt < K; kt += 64) {
    __syncthreads();
#pragma unroll
    for (int i = 0; i < 4; ++i) {
      int flat = i * 4096 + tid * 16;
      int row = flat >> 7;
      int colb = flat & 127;
      gload_lds16(Ab + ((size_t)(m0 + row) * K + kt) * 2 + colb,
                  (char*)lA + i * 4096 + wid * 1024);
    }
#pragma unroll
    for (int i = 0; i < 4; ++i) {
      int flat = i * 4096 + tid * 16;
      int row = flat >> 7;
      int colb = flat & 127;
      gload_lds16(Bb + ((size_t)(n0 + row) * K + kt) * 2 + colb,
                  (char*)lB + i * 4096 + wid * 1024);
    }
    __syncthreads();
#pragma unroll
    for (int ks = 0; ks < 2; ++ks) {
      bf16x8 af[4], bfr[4];
#pragma unroll
      for (int m = 0; m < 4; ++m)
        af[m] = *(const bf16x8*)&lA[(wr + m * 16 + li) * 64 + ks * 32 + lg * 8];
#pragma unroll
      for (int n = 0; n < 4; ++n)
        bfr[n] = *(const bf16x8*)&lB[(wc + n * 16 + li) * 64 + ks * 32 + lg * 8];
#pragma unroll
      for (int m = 0; m < 4; ++m)
#pragma unroll
        for (int n = 0; n < 4; ++n)
          acc[m][n] = __builtin_amdgcn_mfma_f32_16x16x32_bf16(af[m], bfr[n], acc[m][n], 0, 0, 0);
    }
  }

  const int r0 = m0 + wr + lg * 4;
  const int c0 = n0 + wc + li;
#pragma unroll
  for (int m = 0; m < 4; ++m)
#pragma unroll
    for (int n = 0; n < 4; ++n)
#pragma unroll
      for (int r = 0; r < 4; ++r) {
        size_t idx = (size_t)(r0 + m * 16 + r) * N + (c0 + n * 16);
        float v = acc[m][n][r] * scale;
        if (OUT_BF16) ((ushort*)C)[idx] = f2bf(v);
        else          ((float*)C)[idx]  = v;
      }
}

// ---------- flash attention v2 ----------
// 2-phase double-buffered pipeline, swapped QK^T (D[k][q], lane-local softmax),
// defer-max, per-wave P roundtrip (no barrier), XCD-clustered block swizzle.
// One __syncthreads per KV iteration.

__device__ __forceinline__ void stage_tiles(const ushort* K, const ushort* VT,
                                            ushort* lk, ushort* lv,
                                            int b, int h, int kv0, int tid) {
  const int wid = tid >> 6;
#pragma unroll
  for (int i = 0; i < 4; ++i) {
    int flat = i * 4096 + tid * 16;
    int row = flat >> 8;                         // K tile rows are 256 B
    int colb = (flat & 255) ^ ((row & 7) << 4);  // pre-swizzled global source
    gload_lds16((const char*)K + ((size_t)(b * 2048 + kv0 + row) * 2048 + h * 128) * 2 + colb,
                (char*)lk + i * 4096 + wid * 1024);
  }
#pragma unroll
  for (int i = 0; i < 4; ++i) {
    int flat = i * 4096 + tid * 16;
    int row = flat >> 7;                         // VT tile rows are 128 B
    int colb = (flat & 127) ^ ((row & 7) << 4);
    gload_lds16((const char*)VT + ((size_t)((b * 16 + h) * 128 + row) * 2048 + kv0) * 2 + colb,
                (char*)lv + i * 4096 + wid * 1024);
  }
}

__global__ __launch_bounds__(256)
void flash_attn2(const ushort* __restrict__ Q, const ushort* __restrict__ K,
                 const ushort* __restrict__ VT, const uint* __restrict__ maskp,
                 ushort* __restrict__ X) {
  __shared__ ushort lK[2][64 * 128];   // [kv][hd], swizzled
  __shared__ ushort lVT[2][128 * 64];  // [hd][kv], swizzled
  __shared__ ushort lP[4][16 * 64];    // per-wave P^T [q][k], swizzled

  const int tid = threadIdx.x;
  const int wid = tid >> 6;
  const int lane = tid & 63;
  const int lg = lane >> 4, li = lane & 15;

  // XCD-clustered swizzle: all 32 q-tiles of one bh land on one XCD (bid%8)
  const int flat = blockIdx.x;        // 0..2047
  const int xcd = flat & 7;
  const int j = flat >> 3;            // 0..255
  const int bh = xcd * 8 + (j >> 5);  // 8 bh per XCD, qt fastest
  const int qt = j & 31;
  const int b = bh >> 4, h = bh & 15;
  const int q0 = qt * 64;
  const int q_lane = q0 + wid * 16 + li;  // this lane's q row (col of D)

  // Q as MFMA B-operand: col = q = li, k-dim elems hd = kk*32 + lg*8 + 0..7
  bf16x8 bq[4];
  {
    const ushort* qrow = Q + (size_t)(b * 2048 + q_lane) * 2048 + h * 128;
#pragma unroll
    for (int kk = 0; kk < 4; ++kk)
      bq[kk] = *(const bf16x8*)(qrow + kk * 32 + lg * 8);
  }

  const uint* mq = maskp + (size_t)(b * 2048 + q_lane) * 64;
  uint w0 = mq[0], w1 = mq[1];

  f32x4 acc_o[8] = {};  // O^T[hd = f*16 + lg*4 + r][q = li]
  float m = -3e38f, l = 0.f;

  stage_tiles(K, VT, lK[0], lVT[0], b, h, 0, tid);
  __syncthreads();  // compiler drains vmcnt(0) before barrier

  for (int kv0 = 0; kv0 < 2048; kv0 += 64) {
    const int cur = (kv0 >> 6) & 1;
    uint nw0 = 0, nw1 = 0;
    if (kv0 + 64 < 2048) {
      // issue next tile's loads FIRST — latency hides under this tile's compute
      stage_tiles(K, VT, lK[cur ^ 1], lVT[cur ^ 1], b, h, kv0 + 64, tid);
      nw0 = mq[(kv0 + 64) >> 5];
      nw1 = mq[((kv0 + 64) >> 5) + 1];
    }
    const ushort* lk = lK[cur];
    const ushort* lv = lVT[cur];

    // QK^T swapped: A = K-strip (16 k-rows), B = Q cols. accs[n]: k = n*16+lg*4+r
    f32x4 accs[4] = {};
#pragma unroll
    for (int kk = 0; kk < 4; ++kk) {
#pragma unroll
      for (int n = 0; n < 4; ++n) {
        bf16x8 ak = *(const bf16x8*)((const char*)lk + (n * 16 + li) * 256 +
                                     ((kk * 64 + lg * 16) ^ ((li & 7) << 4)));
        accs[n] = __builtin_amdgcn_mfma_f32_16x16x32_bf16(ak, bq[kk], accs[n], 0, 0, 0);
      }
    }

    // mask + lane-local softmax (16 k-values per lane, one q per lane)
    float sv[16];
    float pmax = -3e38f;
#pragma unroll
    for (int n = 0; n < 4; ++n) {
      uint w = (n < 2) ? w0 : w1;
#pragma unroll
      for (int r = 0; r < 4; ++r) {
        int bit = (n & 1) * 16 + lg * 4 + r;
        float s = accs[n][r] + (((w >> bit) & 1u) ? 0.0f : -1e10f);
        sv[n * 4 + r] = s;
        pmax = fmaxf(pmax, s);
      }
    }
    pmax = fmaxf(pmax, __shfl_xor(pmax, 16, 64));
    pmax = fmaxf(pmax, __shfl_xor(pmax, 32, 64));

    // defer-max (T13): rescale only when max grows by > 8
    if (!__all(pmax - m <= 8.0f)) {
      float mnew = fmaxf(m, pmax);
      float alpha = __expf(m - mnew);
      l *= alpha;
#pragma unroll
      for (int f = 0; f < 8; ++f)
#pragma unroll
        for (int r = 0; r < 4; ++r) acc_o[f][r] *= alpha;
      m = mnew;
    }

    float sum = 0.f;
    ushort pb[16];
#pragma unroll
    for (int i = 0; i < 16; ++i) {
      float pv = __expf(sv[i] - m);  // bounded by e^8
      sum += pv;
      pb[i] = f2bf(pv);
    }
    sum += __shfl_xor(sum, 16, 64);
    sum += __shfl_xor(sum, 32, 64);
    l += sum;

    // P^T -> per-wave LDS [q=li][k], lane's k = n*16 + lg*4 + {0..3} (8B packed)
    ushort* lp = lP[wid];
#pragma unroll
    for (int n = 0; n < 4; ++n) {
      union { ushort u[4]; uint2 v; } pk;
      pk.u[0] = pb[n * 4 + 0]; pk.u[1] = pb[n * 4 + 1];
      pk.u[2] = pb[n * 4 + 2]; pk.u[3] = pb[n * 4 + 3];
      *(uint2*)((char*)lp + li * 128 + ((n * 32 + lg * 8) ^ ((li & 7) << 4))) = pk.v;
    }
    // within-wave ds_write -> ds_read: compiler inserts lgkmcnt wait; no barrier

    // PV swapped: A = V^T strip (16 hd-rows), B = P^T cols (q)
#pragma unroll
    for (int kc = 0; kc < 2; ++kc) {
      bf16x8 bp = *(const bf16x8*)((const char*)lp + li * 128 +
                                   ((kc * 64 + lg * 16) ^ ((li & 7) << 4)));
#pragma unroll
      for (int f = 0; f < 8; ++f) {
        bf16x8 av = *(const bf16x8*)((const char*)lv + (f * 16 + li) * 128 +
                                     ((kc * 64 + lg * 16) ^ ((li & 7) << 4)));
        acc_o[f] = __builtin_amdgcn_mfma_f32_16x16x32_bf16(av, bp, acc_o[f], 0, 0, 0);
      }
    }

    w0 = nw0; w1 = nw1;
    __syncthreads();  // next buffer staged+visible; this buffer free to overwrite
  }

  // epilogue: O[q_lane][hd], hd = f*16 + lg*4 + r; 8B packed stores
  const float inv_l = 1.0f / l;
  ushort* xrow = X + (size_t)(b * 2048 + q_lane) * 2048 + h * 128;
#pragma unroll
  for (int f = 0; f < 8; ++f) {
    union { ushort u[4]; uint2 v; } o;
#pragma unroll
    for (int r = 0; r < 4; ++r) o.u[r] = f2bf(acc_o[f][r] * inv_l);
    *(uint2*)(xrow + f * 16 + lg * 4) = o.v;
  }
}

// ---------- launch ----------

extern "C" void kernel_launch(void* const* d_in, const int* in_sizes, int n_in,
                              void* d_out, int out_size, void* d_ws, size_t ws_size,
                              hipStream_t stream) {
  const float* inputs_q  = (const float*)d_in[0];
  const float* inputs_kv = (const float*)d_in[1];
  const int*   mask      = (const int*)d_in[2];
  const float* Wq        = (const float*)d_in[3];
  const float* Wk        = (const float*)d_in[4];
  const float* Wv        = (const float*)d_in[5];
  const float* Wo        = (const float*)d_in[6];
  float* out = (float*)d_out;
  char* ws = (char*)d_ws;

  uint*   maskp = (uint*)(ws + 0);                 //   2,097,152
  ushort* xq    = (ushort*)(ws + 2097152);         //  33,554,432 (reused as VT)
  ushort* xkv   = (ushort*)(ws + 35651584);        //  33,554,432 (reused as X)
  ushort* WqT   = (ushort*)(ws + 69206016);        //   8,388,608
  ushort* WkT   = (ushort*)(ws + 77594624);
  ushort* WvT   = (ushort*)(ws + 85983232);
  ushort* WoT   = (ushort*)(ws + 94371840);
  ushort* Qb    = (ushort*)(ws + 102760448);       //  33,554,432
  ushort* Kb    = (ushort*)(ws + 136314880);
  ushort* Vb    = (ushort*)(ws + 169869312);
  ushort* VTb   = xq;   // V^T, written after xq dead
  ushort* Xb    = xkv;  // attention output, written after xkv dead

  const long NE = 8192L * 2048;
  conv_bf16<<<8192, 256, 0, stream>>>(inputs_q,  xq,  NE);
  conv_bf16<<<8192, 256, 0, stream>>>(inputs_kv, xkv, NE);

  dim3 tb(32, 8);
  transpose_to_bf16<float><<<dim3(64, 64, 1), tb, 0, stream>>>(Wq, WqT, 2048, 2048);
  transpose_to_bf16<float><<<dim3(64, 64, 1), tb, 0, stream>>>(Wk, WkT, 2048, 2048);
  transpose_to_bf16<float><<<dim3(64, 64, 1), tb, 0, stream>>>(Wv, WvT, 2048, 2048);
  transpose_to_bf16<float><<<dim3(64, 64, 1), tb, 0, stream>>>(Wo, WoT, 2048, 2048);

  pack_mask<<<2048, 256, 0, stream>>>(mask, maskp);

  const float qscale = 0.08838834764831845f;  // 1/sqrt(128)
  gemm_bt<1><<<dim3(16, 64), 256, 0, stream>>>(xq,  WqT, Qb, 8192, 2048, 2048, qscale);
  gemm_bt<1><<<dim3(16, 64), 256, 0, stream>>>(xkv, WkT, Kb, 8192, 2048, 2048, 1.0f);
  gemm_bt<1><<<dim3(16, 64), 256, 0, stream>>>(xkv, WvT, Vb, 8192, 2048, 2048, 1.0f);

  transpose_to_bf16<ushort><<<dim3(64, 64, 4), tb, 0, stream>>>(Vb, VTb, 2048, 2048);

  flash_attn2<<<2048, 256, 0, stream>>>(Qb, Kb, VTb, maskp, Xb);

  gemm_bt<0><<<dim3(16, 64), 256, 0, stream>>>(Xb, WoT, out, 8192, 2048, 2048, 1.0f);
}